// Round 8
// baseline (7112.102 us; speedup 1.0000x reference)
//
#include <hip/hip_runtime.h>
#include <stdint.h>
#include <stddef.h>

// Problem dims
#define B_  128
#define S_  48
#define E_  620
#define EP  640    // E padded to multiple of 32 (zeros)
#define H_  2400
#define N3  7200   // 3*H (r,i,n concatenated)
#define KH  2400
#define NBLK 450     // persistent blocks: 225 n-slices x 2 k-halves, 2/CU
#define KIT  38      // uniform k-iters per block (z=1 pads iter 37 with zeros)
#define P1_ITERS 20  // phase-1 K = 640 = 20 x 32

typedef _Float16 half_t;
typedef __attribute__((ext_vector_type(8))) _Float16 half8;
typedef __attribute__((ext_vector_type(4))) float    floatx4;

// Workgroup barrier that waits ONLY on LDS ops (phase-1 gemm_x).
__device__ __forceinline__ void lds_barrier() {
  __builtin_amdgcn_sched_barrier(0);
  __builtin_amdgcn_s_waitcnt(0xC07F);   // vmcnt(63) expcnt(7) lgkmcnt(0)
  __builtin_amdgcn_s_barrier();
  __builtin_amdgcn_sched_barrier(0);
}

// Device-scope grid barrier; correctness proven in r6 (225 blocks, passed).
__device__ __forceinline__ void grid_barrier(int* bar) {
  __syncthreads();
  if (threadIdx.x == 0) {
    __threadfence();   // release: drain this block's global writes
    int g = __hip_atomic_load(&bar[1], __ATOMIC_RELAXED, __HIP_MEMORY_SCOPE_AGENT);
    if (__hip_atomic_fetch_add(&bar[0], 1, __ATOMIC_ACQ_REL,
                               __HIP_MEMORY_SCOPE_AGENT) == NBLK - 1) {
      __hip_atomic_store(&bar[0], 0, __ATOMIC_RELAXED, __HIP_MEMORY_SCOPE_AGENT);
      __hip_atomic_fetch_add(&bar[1], 1, __ATOMIC_ACQ_REL, __HIP_MEMORY_SCOPE_AGENT);
    } else {
      while (__hip_atomic_load(&bar[1], __ATOMIC_RELAXED,
                               __HIP_MEMORY_SCOPE_AGENT) == g)
        __builtin_amdgcn_s_sleep(2);
    }
    __threadfence();   // acquire: invalidate stale cached lines
  }
  __syncthreads();
}

// ---- x = fp16(emb[tokens]), padded [6144, 640] ----
__global__ void gather_cast_x(const int* __restrict__ tokens,
                              const float* __restrict__ emb,
                              half_t* __restrict__ xb) {
  int idx = blockIdx.x * 256 + threadIdx.x;       // over 6144*EP
  int m = idx / EP, c = idx - m * EP;
  float v = 0.f;
  if (c < E_) v = emb[(size_t)tokens[m] * E_ + c];
  xb[idx] = (half_t)v;
}

// ---- W_i = fp16 concat(W_ir,W_ii,W_in) [7200, 640]; bias concat [7200] ----
__global__ void convert_wi(const float* __restrict__ Wir, const float* __restrict__ Wii,
                           const float* __restrict__ Win,
                           const float* __restrict__ bir, const float* __restrict__ bii,
                           const float* __restrict__ bin,
                           half_t* __restrict__ Wi, float* __restrict__ bias) {
  int idx = blockIdx.x * 256 + threadIdx.x;       // over N3*EP
  int r = idx / EP, c = idx - r * EP;
  const float* W = (r < H_) ? Wir : (r < 2*H_ ? Wii : Win);
  int rr = (r < H_) ? r : (r < 2*H_ ? r - H_ : r - 2*H_);
  float v = (c < E_) ? W[(size_t)rr * E_ + c] : 0.f;
  Wi[idx] = (half_t)v;
  if (c == 0) {
    const float* bb = (r < H_) ? bir : (r < 2*H_ ? bii : bin);
    bias[r] = bb[rr];
  }
}

// ---- Wf = fp16 concat(W_hr,W_hi,W_hn) [7200, 2400] ----
__global__ void convert_wh(const float* __restrict__ Whr, const float* __restrict__ Whi,
                           const float* __restrict__ Whn, half_t* __restrict__ Wf) {
  int idx = blockIdx.x * 256 + threadIdx.x;       // over N3*KH
  int r = idx / KH, c = idx - r * KH;
  const float* W = (r < H_) ? Whr : (r < 2*H_ ? Whi : Whn);
  int rr = (r < H_) ? r : (r < 2*H_ ? r - H_ : r - 2*H_);
  Wf[idx] = (half_t)W[(size_t)rr * KH + c];
}

__global__ void init_h(float* __restrict__ h, half_t* __restrict__ hh,
                       int* __restrict__ bar) {
  int idx = blockIdx.x * 256 + threadIdx.x;       // over B_*H_
  h[idx] = 0.f;
  hh[idx] = (half_t)0.f;
  if (idx == 0) { bar[0] = 0; bar[1] = 0; }
}

// ---- Phase 1: gx = fp16( xb @ Wi^T + bias )  [6144 x 7200], K=640 ----
__global__ __launch_bounds__(256, 2) void gemm_x(
    const half_t* __restrict__ A,   // xb [6144 x 640]
    const half_t* __restrict__ Bm,  // Wi [7200 x 640]
    half_t* __restrict__ C,         // gx [6144 x 7200]
    const float* __restrict__ bias)
{
  __shared__ half_t As[2][4096];
  __shared__ half_t Bs[2][4096];

  const int tid = threadIdx.x;
  const int lane = tid & 63;
  const int w = tid >> 6;
  const int m0 = blockIdx.x * 128;
  const int n0 = blockIdx.y * 128;
  const int wm = (w >> 1) * 64, wn = (w & 1) * 64;

  const int c0 = tid, c1 = tid + 256;
  const int rA0 = m0 + (c0 >> 6) * 16 + (c0 & 15), q0 = ((c0 >> 4) & 3) * 8;
  const int rA1 = m0 + (c1 >> 6) * 16 + (c1 & 15), q1 = ((c1 >> 4) & 3) * 8;
  int rB0 = n0 + (c0 >> 6) * 16 + (c0 & 15); if (rB0 >= N3) rB0 = N3 - 1;
  int rB1 = n0 + (c1 >> 6) * 16 + (c1 & 15); if (rB1 >= N3) rB1 = N3 - 1;
  const half_t* pA0 = A  + (size_t)rA0 * EP + q0;
  const half_t* pA1 = A  + (size_t)rA1 * EP + q1;
  const half_t* pB0 = Bm + (size_t)rB0 * EP + q0;
  const half_t* pB1 = Bm + (size_t)rB1 * EP + q1;

  floatx4 acc[4][4] = {};

  half8 ga0 = *(const half8*)(pA0);
  half8 ga1 = *(const half8*)(pA1);
  half8 gb0 = *(const half8*)(pB0);
  half8 gb1 = *(const half8*)(pB1);
  *(half8*)(As[0] + c0 * 8) = ga0;
  *(half8*)(As[0] + c1 * 8) = ga1;
  *(half8*)(Bs[0] + c0 * 8) = gb0;
  *(half8*)(Bs[0] + c1 * 8) = gb1;
  ga0 = *(const half8*)(pA0 + 32);
  ga1 = *(const half8*)(pA1 + 32);
  gb0 = *(const half8*)(pB0 + 32);
  gb1 = *(const half8*)(pB1 + 32);
  lds_barrier();

  #pragma unroll
  for (int i = 0; i < P1_ITERS; ++i) {
    const int cur = i & 1, nxt = cur ^ 1;
    half8 a[4], b[4];
    #pragma unroll
    for (int f = 0; f < 4; ++f) {
      a[f] = *(const half8*)(As[cur] + (((wm >> 4) + f) * 64 + lane) * 8);
      b[f] = *(const half8*)(Bs[cur] + (((wn >> 4) + f) * 64 + lane) * 8);
    }
    if (i + 1 < P1_ITERS) {
      *(half8*)(As[nxt] + c0 * 8) = ga0;
      *(half8*)(As[nxt] + c1 * 8) = ga1;
      *(half8*)(Bs[nxt] + c0 * 8) = gb0;
      *(half8*)(Bs[nxt] + c1 * 8) = gb1;
    }
    if (i + 2 < P1_ITERS) {
      int ko = (i + 2) * 32;
      ga0 = *(const half8*)(pA0 + ko);
      ga1 = *(const half8*)(pA1 + ko);
      gb0 = *(const half8*)(pB0 + ko);
      gb1 = *(const half8*)(pB1 + ko);
    }
    #pragma unroll
    for (int mf = 0; mf < 4; ++mf)
      #pragma unroll
      for (int nf = 0; nf < 4; ++nf)
        acc[mf][nf] = __builtin_amdgcn_mfma_f32_16x16x32_f16(
            a[mf], b[nf], acc[mf][nf], 0, 0, 0);
    if (i + 1 < P1_ITERS) lds_barrier();
  }

  const int col = lane & 15, qr = (lane >> 4) * 4;
  #pragma unroll
  for (int nf = 0; nf < 4; ++nf) {
    int n = n0 + wn + nf * 16 + col;
    if (n >= N3) continue;
    float bv = bias[n];
    #pragma unroll
    for (int mf = 0; mf < 4; ++mf)
      #pragma unroll
      for (int r = 0; r < 4; ++r)
        C[(size_t)(m0 + wm + mf * 16 + qr + r) * N3 + n] =
            (half_t)(acc[mf][nf][r] + bv);
  }
}

// ---- Phase 2: persistent weight-stationary GRU scan (v2) ----
// 450 blocks (225 n-slices x 2 k-halves) x 256 thr, 2 blocks/CU (76 KB LDS),
// 8 waves/CU. Weights loaded to LDS ONCE (frag-major, conflict-free).
// Per step: each wave computes 32m x 32n x 1216k partial via fully-unrolled
// 38-iter MFMA loop (A from global/L2 via depth-4 register ring, B ds_read),
// writes f32 partial to Gp[z]; grid barrier; fused gate; grid barrier.
__global__ __launch_bounds__(256, 2) void gru_scan(
    const half_t* __restrict__ Wf,   // [7200][2400]
    const half_t* __restrict__ gx,   // [6144][7200]
    float* __restrict__ Gp,          // [2][128][7200]
    float* __restrict__ h,           // [128][2400]
    half_t* __restrict__ hh,         // [128][2400] (+64 pad)
    const int* __restrict__ lengths,
    float* __restrict__ out,         // [128][2400]
    int* __restrict__ bar)
{
  __shared__ half_t Ws[KIT * 128 * 8];   // 76 KB: 32 n x 1216 k, frag-major

  const int tid = threadIdx.x;
  const int lane = tid & 63;
  const int w = tid >> 6;
  const int nb = blockIdx.x >> 1;        // 0..224
  const int z  = blockIdx.x & 1;
  const int n0 = nb * 32;
  const int kb = z ? 1216 : 0;           // z=1 covers 1184 real k + 32 zeros

  // one-time weight load: chunk c -> kt=c>>7, j=(c>>6)&1, l=c&63
  for (int c = tid; c < KIT * 128; c += 256) {
    int kt = c >> 7, j = (c >> 6) & 1, l = c & 63;
    int n = n0 + j * 16 + (l & 15);
    int k = kb + kt * 32 + (l >> 4) * 8;
    half8 v = {};
    if (k < KH) v = *(const half8*)&Wf[(size_t)n * KH + k];
    *(half8*)&Ws[c * 8] = v;
  }
  __syncthreads();

  const int fm = lane & 15;
  const int fk = (lane >> 4) * 8;
  const half_t* pa0 = hh + (size_t)(w * 32 + fm) * KH + kb + fk;      // m-tile 2w
  const half_t* pa1 = hh + (size_t)(w * 32 + 16 + fm) * KH + kb + fk; // m-tile 2w+1
  const int col = lane & 15, qr = (lane >> 4) * 4;
  float* G = Gp + (size_t)z * (B_ * N3);

  #pragma unroll 1
  for (int t = 0; t < S_; ++t) {
    floatx4 acc[2][2] = {};
    half8 aR[4][2];                      // A ring, depth 4
    #pragma unroll
    for (int d = 0; d < 4; ++d) {
      aR[d][0] = *(const half8*)(pa0 + d * 32);
      aR[d][1] = *(const half8*)(pa1 + d * 32);
    }
    #pragma unroll
    for (int i = 0; i < KIT; ++i) {
      half8 a0 = aR[i & 3][0], a1 = aR[i & 3][1];
      half8 b0 = *(const half8*)&Ws[(i * 128 + lane) * 8];
      half8 b1 = *(const half8*)&Ws[(i * 128 + 64 + lane) * 8];
      if (i + 4 < KIT) {
        int ko = (i + 4) * 32;
        aR[i & 3][0] = *(const half8*)(pa0 + ko);
        aR[i & 3][1] = *(const half8*)(pa1 + ko);
      }
      acc[0][0] = __builtin_amdgcn_mfma_f32_16x16x32_f16(a0, b0, acc[0][0], 0, 0, 0);
      acc[0][1] = __builtin_amdgcn_mfma_f32_16x16x32_f16(a0, b1, acc[0][1], 0, 0, 0);
      acc[1][0] = __builtin_amdgcn_mfma_f32_16x16x32_f16(a1, b0, acc[1][0], 0, 0, 0);
      acc[1][1] = __builtin_amdgcn_mfma_f32_16x16x32_f16(a1, b1, acc[1][1], 0, 0, 0);
    }
    #pragma unroll
    for (int mf = 0; mf < 2; ++mf)
      #pragma unroll
      for (int nf = 0; nf < 2; ++nf)
        #pragma unroll
        for (int r = 0; r < 4; ++r)
          G[(size_t)(w * 32 + mf * 16 + qr + r) * N3 + n0 + nf * 16 + col] =
              acc[mf][nf][r];

    grid_barrier(bar);

    // fused gate update (grid-strided over B_*H_)
    for (int idx = blockIdx.x * 256 + tid; idx < B_ * H_; idx += NBLK * 256) {
      int m = idx / H_;
      int j = idx - m * H_;
      size_t rx = ((size_t)m * S_ + t) * N3;
      float xr = (float)gx[rx + j];
      float xi = (float)gx[rx + H_ + j];
      float xn = (float)gx[rx + 2 * H_ + j];
      size_t gm = (size_t)m * N3;
      float Gr = Gp[gm + j]           + Gp[(size_t)B_ * N3 + gm + j];
      float Gi = Gp[gm + H_ + j]      + Gp[(size_t)B_ * N3 + gm + H_ + j];
      float Gn = Gp[gm + 2 * H_ + j]  + Gp[(size_t)B_ * N3 + gm + 2 * H_ + j];
      float ho = h[idx];
      float r  = 1.f / (1.f + __expf(-(xr + Gr)));
      float ig = 1.f / (1.f + __expf(-(xi + Gi)));
      float nn = tanhf(xn + r * Gn);
      float hn = (1.f - ig) * nn + ig * ho;
      h[idx]  = hn;
      hh[idx] = (half_t)hn;
      int lc = lengths[m] - 1;
      lc = lc < 0 ? 0 : (lc > S_ - 1 ? S_ - 1 : lc);
      if (t == lc) out[idx] = hn;
    }

    grid_barrier(bar);
  }
}

extern "C" void kernel_launch(void* const* d_in, const int* in_sizes, int n_in,
                              void* d_out, int out_size, void* d_ws, size_t ws_size,
                              hipStream_t stream)
{
  const int*   tokens  = (const int*)d_in[0];
  const int*   lengths = (const int*)d_in[1];
  const float* emb = (const float*)d_in[2];
  const float* Wir = (const float*)d_in[3];
  const float* Wii = (const float*)d_in[4];
  const float* Win = (const float*)d_in[5];
  const float* bir = (const float*)d_in[6];
  const float* bii = (const float*)d_in[7];
  const float* bin = (const float*)d_in[8];
  const float* Whr = (const float*)d_in[9];
  const float* Whi = (const float*)d_in[10];
  const float* Whn = (const float*)d_in[11];
  float* out = (float*)d_out;

  char* ws = (char*)d_ws;
  size_t off = 0;
  auto alloc = [&](size_t bytes) {
    void* p = ws + off;
    off = (off + bytes + 255) & ~(size_t)255;
    return p;
  };
  half_t* xb   = (half_t*)alloc((size_t)(B_ * S_) * EP * 2);   //  7.9 MB
  half_t* Wi   = (half_t*)alloc((size_t)N3 * EP * 2);          //  9.2 MB
  half_t* Wf   = (half_t*)alloc((size_t)N3 * KH * 2);          // 34.6 MB
  float*  bias = (float*)alloc((size_t)N3 * 4);
  half_t* gx   = (half_t*)alloc((size_t)(B_ * S_) * N3 * 2);   // 88.5 MB
  float*  Gp   = (float*)alloc((size_t)2 * B_ * N3 * 4);       //  7.4 MB
  float*  h    = (float*)alloc((size_t)B_ * H_ * 4);
  half_t* hh   = (half_t*)alloc(((size_t)B_ * KH + 64) * 2);   // +64 pad (z=1 tail read x0 weights)
  int*    bar  = (int*)alloc(256);

  gather_cast_x<<<(B_ * S_ * EP) / 256, 256, 0, stream>>>(tokens, emb, xb);
  convert_wi<<<(N3 * EP) / 256, 256, 0, stream>>>(Wir, Wii, Win, bir, bii, bin, Wi, bias);
  convert_wh<<<(N3 * KH) / 256, 256, 0, stream>>>(Whr, Whi, Whn, Wf);
  init_h<<<(B_ * H_) / 256, 256, 0, stream>>>(h, hh, bar);

  // Phase 1: gates_x = fp16( x @ W_i^T + b )   [6144 x 7200]
  gemm_x<<<dim3(48, 57), 256, 0, stream>>>(xb, Wi, gx, bias);

  // Phase 2: one persistent weight-stationary kernel runs all 48 steps
  gru_scan<<<NBLK, 256, 0, stream>>>(Wf, gx, Gp, h, hh, lengths, out, bar);
}

// Round 9
// 3499.511 us; speedup vs baseline: 2.0323x; 2.0323x over previous
//
#include <hip/hip_runtime.h>
#include <stdint.h>
#include <stddef.h>

// Problem dims
#define B_  128
#define S_  48
#define E_  620
#define EP  640    // E padded to multiple of 32 (zeros)
#define H_  2400
#define N3  7200   // 3*H (r,i,n concatenated)
#define KH  2400
#define NBLK 450     // persistent blocks: 225 n-slices x 2 k-halves, 2/CU
#define KIT  38      // uniform k-iters per block (z=1 pads iter 37 with zeros)
#define P1_ITERS 20  // phase-1 K = 640 = 20 x 32

typedef _Float16 half_t;
typedef __attribute__((ext_vector_type(8))) _Float16 half8;
typedef __attribute__((ext_vector_type(4))) float    floatx4;

// Workgroup barrier that waits ONLY on LDS ops (phase-1 gemm_x).
__device__ __forceinline__ void lds_barrier() {
  __builtin_amdgcn_sched_barrier(0);
  __builtin_amdgcn_s_waitcnt(0xC07F);   // vmcnt(63) expcnt(7) lgkmcnt(0)
  __builtin_amdgcn_s_barrier();
  __builtin_amdgcn_sched_barrier(0);
}

// Grid barrier v2: flag-array + master-poll + release word.
// NO same-address RMW (r8's fetch_add on one line serialized 450 leaders at
// ~300-500cyc each = ~65us/barrier). Stores/loads only:
//  - leader b stores gen to flags[b*16] (450 distinct 64B lines, parallel)
//  - block 0 polls all flags (256 thr in parallel), then stores gen to rel
//  - all leaders spin on rel (read-only, broadcast-friendly)
// Fence protocol identical to r6/r8 (proven correct).
__device__ __forceinline__ void grid_barrier(uint32_t* flags, uint32_t* rel,
                                             uint32_t gen) {
  __syncthreads();
  const int tid = threadIdx.x;
  if (tid == 0) {
    __threadfence();   // release: my G/hh writes visible before flag
    __hip_atomic_store(&flags[blockIdx.x * 16], gen, __ATOMIC_RELAXED,
                       __HIP_MEMORY_SCOPE_AGENT);
  }
  if (blockIdx.x == 0) {
    for (int i = tid; i < NBLK; i += 256) {
      while (__hip_atomic_load(&flags[i * 16], __ATOMIC_RELAXED,
                               __HIP_MEMORY_SCOPE_AGENT) != gen)
        __builtin_amdgcn_s_sleep(1);
    }
    __syncthreads();
    if (tid == 0) {
      __threadfence();
      __hip_atomic_store(rel, gen, __ATOMIC_RELAXED, __HIP_MEMORY_SCOPE_AGENT);
    }
  }
  if (tid == 0) {
    while (__hip_atomic_load(rel, __ATOMIC_RELAXED,
                             __HIP_MEMORY_SCOPE_AGENT) != gen)
      __builtin_amdgcn_s_sleep(1);
    __threadfence();   // acquire: invalidate stale cached lines
  }
  __syncthreads();
}

// ---- x = fp16(emb[tokens]), padded [6144, 640] ----
__global__ void gather_cast_x(const int* __restrict__ tokens,
                              const float* __restrict__ emb,
                              half_t* __restrict__ xb) {
  int idx = blockIdx.x * 256 + threadIdx.x;       // over 6144*EP
  int m = idx / EP, c = idx - m * EP;
  float v = 0.f;
  if (c < E_) v = emb[(size_t)tokens[m] * E_ + c];
  xb[idx] = (half_t)v;
}

// ---- W_i = fp16 concat(W_ir,W_ii,W_in) [7200, 640]; bias concat [7200] ----
__global__ void convert_wi(const float* __restrict__ Wir, const float* __restrict__ Wii,
                           const float* __restrict__ Win,
                           const float* __restrict__ bir, const float* __restrict__ bii,
                           const float* __restrict__ bin,
                           half_t* __restrict__ Wi, float* __restrict__ bias) {
  int idx = blockIdx.x * 256 + threadIdx.x;       // over N3*EP
  int r = idx / EP, c = idx - r * EP;
  const float* W = (r < H_) ? Wir : (r < 2*H_ ? Wii : Win);
  int rr = (r < H_) ? r : (r < 2*H_ ? r - H_ : r - 2*H_);
  float v = (c < E_) ? W[(size_t)rr * E_ + c] : 0.f;
  Wi[idx] = (half_t)v;
  if (c == 0) {
    const float* bb = (r < H_) ? bir : (r < 2*H_ ? bii : bin);
    bias[r] = bb[rr];
  }
}

// ---- Wf = fp16 concat(W_hr,W_hi,W_hn) [7200, 2400] ----
__global__ void convert_wh(const float* __restrict__ Whr, const float* __restrict__ Whi,
                           const float* __restrict__ Whn, half_t* __restrict__ Wf) {
  int idx = blockIdx.x * 256 + threadIdx.x;       // over N3*KH
  int r = idx / KH, c = idx - r * KH;
  const float* W = (r < H_) ? Whr : (r < 2*H_ ? Whi : Whn);
  int rr = (r < H_) ? r : (r < 2*H_ ? r - H_ : r - 2*H_);
  Wf[idx] = (half_t)W[(size_t)rr * KH + c];
}

__global__ void init_h(float* __restrict__ h, half_t* __restrict__ hh,
                       uint32_t* __restrict__ barbuf) {
  int idx = blockIdx.x * 256 + threadIdx.x;       // over B_*H_
  h[idx] = 0.f;
  hh[idx] = (half_t)0.f;
  if (idx < 16384) barbuf[idx] = 0;               // flags + rel
}

// ---- Phase 1: gx = fp16( xb @ Wi^T + bias )  [6144 x 7200], K=640 ----
__global__ __launch_bounds__(256, 2) void gemm_x(
    const half_t* __restrict__ A,   // xb [6144 x 640]
    const half_t* __restrict__ Bm,  // Wi [7200 x 640]
    half_t* __restrict__ C,         // gx [6144 x 7200]
    const float* __restrict__ bias)
{
  __shared__ half_t As[2][4096];
  __shared__ half_t Bs[2][4096];

  const int tid = threadIdx.x;
  const int lane = tid & 63;
  const int w = tid >> 6;
  const int m0 = blockIdx.x * 128;
  const int n0 = blockIdx.y * 128;
  const int wm = (w >> 1) * 64, wn = (w & 1) * 64;

  const int c0 = tid, c1 = tid + 256;
  const int rA0 = m0 + (c0 >> 6) * 16 + (c0 & 15), q0 = ((c0 >> 4) & 3) * 8;
  const int rA1 = m0 + (c1 >> 6) * 16 + (c1 & 15), q1 = ((c1 >> 4) & 3) * 8;
  int rB0 = n0 + (c0 >> 6) * 16 + (c0 & 15); if (rB0 >= N3) rB0 = N3 - 1;
  int rB1 = n0 + (c1 >> 6) * 16 + (c1 & 15); if (rB1 >= N3) rB1 = N3 - 1;
  const half_t* pA0 = A  + (size_t)rA0 * EP + q0;
  const half_t* pA1 = A  + (size_t)rA1 * EP + q1;
  const half_t* pB0 = Bm + (size_t)rB0 * EP + q0;
  const half_t* pB1 = Bm + (size_t)rB1 * EP + q1;

  floatx4 acc[4][4] = {};

  half8 ga0 = *(const half8*)(pA0);
  half8 ga1 = *(const half8*)(pA1);
  half8 gb0 = *(const half8*)(pB0);
  half8 gb1 = *(const half8*)(pB1);
  *(half8*)(As[0] + c0 * 8) = ga0;
  *(half8*)(As[0] + c1 * 8) = ga1;
  *(half8*)(Bs[0] + c0 * 8) = gb0;
  *(half8*)(Bs[0] + c1 * 8) = gb1;
  ga0 = *(const half8*)(pA0 + 32);
  ga1 = *(const half8*)(pA1 + 32);
  gb0 = *(const half8*)(pB0 + 32);
  gb1 = *(const half8*)(pB1 + 32);
  lds_barrier();

  #pragma unroll
  for (int i = 0; i < P1_ITERS; ++i) {
    const int cur = i & 1, nxt = cur ^ 1;
    half8 a[4], b[4];
    #pragma unroll
    for (int f = 0; f < 4; ++f) {
      a[f] = *(const half8*)(As[cur] + (((wm >> 4) + f) * 64 + lane) * 8);
      b[f] = *(const half8*)(Bs[cur] + (((wn >> 4) + f) * 64 + lane) * 8);
    }
    if (i + 1 < P1_ITERS) {
      *(half8*)(As[nxt] + c0 * 8) = ga0;
      *(half8*)(As[nxt] + c1 * 8) = ga1;
      *(half8*)(Bs[nxt] + c0 * 8) = gb0;
      *(half8*)(Bs[nxt] + c1 * 8) = gb1;
    }
    if (i + 2 < P1_ITERS) {
      int ko = (i + 2) * 32;
      ga0 = *(const half8*)(pA0 + ko);
      ga1 = *(const half8*)(pA1 + ko);
      gb0 = *(const half8*)(pB0 + ko);
      gb1 = *(const half8*)(pB1 + ko);
    }
    #pragma unroll
    for (int mf = 0; mf < 4; ++mf)
      #pragma unroll
      for (int nf = 0; nf < 4; ++nf)
        acc[mf][nf] = __builtin_amdgcn_mfma_f32_16x16x32_f16(
            a[mf], b[nf], acc[mf][nf], 0, 0, 0);
    if (i + 1 < P1_ITERS) lds_barrier();
  }

  const int col = lane & 15, qr = (lane >> 4) * 4;
  #pragma unroll
  for (int nf = 0; nf < 4; ++nf) {
    int n = n0 + wn + nf * 16 + col;
    if (n >= N3) continue;
    float bv = bias[n];
    #pragma unroll
    for (int mf = 0; mf < 4; ++mf)
      #pragma unroll
      for (int r = 0; r < 4; ++r)
        C[(size_t)(m0 + wm + mf * 16 + qr + r) * N3 + n] =
            (half_t)(acc[mf][nf][r] + bv);
  }
}

// ---- Phase 2: persistent weight-stationary GRU scan (v3: fast barrier) ----
// 450 blocks (225 n-slices x 2 k-halves) x 256 thr, 2 blocks/CU (76 KB LDS),
// 8 waves/CU. Weights in LDS ONCE (frag-major, conflict-free). Per step:
// 38-iter fully-unrolled MFMA loop (A via depth-4 global register ring,
// B ds_read_b128), f32 partial to Gp[z]; grid barrier; fused gate; barrier.
__global__ __launch_bounds__(256, 2) void gru_scan(
    const half_t* __restrict__ Wf,   // [7200][2400]
    const half_t* __restrict__ gx,   // [6144][7200]
    float* __restrict__ Gp,          // [2][128][7200]
    float* __restrict__ h,           // [128][2400]
    half_t* __restrict__ hh,         // [128][2400] (+64 pad)
    const int* __restrict__ lengths,
    float* __restrict__ out,         // [128][2400]
    uint32_t* __restrict__ barbuf)   // [16384]: flags at 0, rel at 15872
{
  __shared__ half_t Ws[KIT * 128 * 8];   // 76 KB: 32 n x 1216 k, frag-major

  const int tid = threadIdx.x;
  const int lane = tid & 63;
  const int w = tid >> 6;
  const int nb = blockIdx.x >> 1;        // 0..224
  const int z  = blockIdx.x & 1;
  const int n0 = nb * 32;
  const int kb = z ? 1216 : 0;           // z=1 covers 1184 real k + 32 zeros

  uint32_t* flags = barbuf;
  uint32_t* rel   = barbuf + 15872;

  // one-time weight load: chunk c -> kt=c>>7, j=(c>>6)&1, l=c&63
  for (int c = tid; c < KIT * 128; c += 256) {
    int kt = c >> 7, j = (c >> 6) & 1, l = c & 63;
    int n = n0 + j * 16 + (l & 15);
    int k = kb + kt * 32 + (l >> 4) * 8;
    half8 v = {};
    if (k < KH) v = *(const half8*)&Wf[(size_t)n * KH + k];
    *(half8*)&Ws[c * 8] = v;
  }
  __syncthreads();

  const int fm = lane & 15;
  const int fk = (lane >> 4) * 8;
  const half_t* pa0 = hh + (size_t)(w * 32 + fm) * KH + kb + fk;      // m-tile 2w
  const half_t* pa1 = hh + (size_t)(w * 32 + 16 + fm) * KH + kb + fk; // m-tile 2w+1
  const int col = lane & 15, qr = (lane >> 4) * 4;
  float* G = Gp + (size_t)z * (B_ * N3);
  uint32_t gen = 0;

  #pragma unroll 1
  for (int t = 0; t < S_; ++t) {
    floatx4 acc[2][2] = {};
    half8 aR[4][2];                      // A ring, depth 4
    #pragma unroll
    for (int d = 0; d < 4; ++d) {
      aR[d][0] = *(const half8*)(pa0 + d * 32);
      aR[d][1] = *(const half8*)(pa1 + d * 32);
    }
    #pragma unroll
    for (int i = 0; i < KIT; ++i) {
      half8 a0 = aR[i & 3][0], a1 = aR[i & 3][1];
      half8 b0 = *(const half8*)&Ws[(i * 128 + lane) * 8];
      half8 b1 = *(const half8*)&Ws[(i * 128 + 64 + lane) * 8];
      if (i + 4 < KIT) {
        int ko = (i + 4) * 32;
        aR[i & 3][0] = *(const half8*)(pa0 + ko);
        aR[i & 3][1] = *(const half8*)(pa1 + ko);
      }
      acc[0][0] = __builtin_amdgcn_mfma_f32_16x16x32_f16(a0, b0, acc[0][0], 0, 0, 0);
      acc[0][1] = __builtin_amdgcn_mfma_f32_16x16x32_f16(a0, b1, acc[0][1], 0, 0, 0);
      acc[1][0] = __builtin_amdgcn_mfma_f32_16x16x32_f16(a1, b0, acc[1][0], 0, 0, 0);
      acc[1][1] = __builtin_amdgcn_mfma_f32_16x16x32_f16(a1, b1, acc[1][1], 0, 0, 0);
    }
    #pragma unroll
    for (int mf = 0; mf < 2; ++mf)
      #pragma unroll
      for (int nf = 0; nf < 2; ++nf)
        #pragma unroll
        for (int r = 0; r < 4; ++r)
          G[(size_t)(w * 32 + mf * 16 + qr + r) * N3 + n0 + nf * 16 + col] =
              acc[mf][nf][r];

    grid_barrier(flags, rel, ++gen);

    // fused gate update (grid-strided over B_*H_)
    for (int idx = blockIdx.x * 256 + tid; idx < B_ * H_; idx += NBLK * 256) {
      int m = idx / H_;
      int j = idx - m * H_;
      size_t rx = ((size_t)m * S_ + t) * N3;
      float xr = (float)gx[rx + j];
      float xi = (float)gx[rx + H_ + j];
      float xn = (float)gx[rx + 2 * H_ + j];
      size_t gm = (size_t)m * N3;
      float Gr = Gp[gm + j]           + Gp[(size_t)B_ * N3 + gm + j];
      float Gi = Gp[gm + H_ + j]      + Gp[(size_t)B_ * N3 + gm + H_ + j];
      float Gn = Gp[gm + 2 * H_ + j]  + Gp[(size_t)B_ * N3 + gm + 2 * H_ + j];
      float ho = h[idx];
      float r  = 1.f / (1.f + __expf(-(xr + Gr)));
      float ig = 1.f / (1.f + __expf(-(xi + Gi)));
      float nn = tanhf(xn + r * Gn);
      float hn = (1.f - ig) * nn + ig * ho;
      h[idx]  = hn;
      hh[idx] = (half_t)hn;
      int lc = lengths[m] - 1;
      lc = lc < 0 ? 0 : (lc > S_ - 1 ? S_ - 1 : lc);
      if (t == lc) out[idx] = hn;
    }

    grid_barrier(flags, rel, ++gen);
  }
}

extern "C" void kernel_launch(void* const* d_in, const int* in_sizes, int n_in,
                              void* d_out, int out_size, void* d_ws, size_t ws_size,
                              hipStream_t stream)
{
  const int*   tokens  = (const int*)d_in[0];
  const int*   lengths = (const int*)d_in[1];
  const float* emb = (const float*)d_in[2];
  const float* Wir = (const float*)d_in[3];
  const float* Wii = (const float*)d_in[4];
  const float* Win = (const float*)d_in[5];
  const float* bir = (const float*)d_in[6];
  const float* bii = (const float*)d_in[7];
  const float* bin = (const float*)d_in[8];
  const float* Whr = (const float*)d_in[9];
  const float* Whi = (const float*)d_in[10];
  const float* Whn = (const float*)d_in[11];
  float* out = (float*)d_out;

  char* ws = (char*)d_ws;
  size_t off = 0;
  auto alloc = [&](size_t bytes) {
    void* p = ws + off;
    off = (off + bytes + 255) & ~(size_t)255;
    return p;
  };
  half_t*   xb   = (half_t*)alloc((size_t)(B_ * S_) * EP * 2);   //  7.9 MB
  half_t*   Wi   = (half_t*)alloc((size_t)N3 * EP * 2);          //  9.2 MB
  half_t*   Wf   = (half_t*)alloc((size_t)N3 * KH * 2);          // 34.6 MB
  float*    bias = (float*)alloc((size_t)N3 * 4);
  half_t*   gx   = (half_t*)alloc((size_t)(B_ * S_) * N3 * 2);   // 88.5 MB
  float*    Gp   = (float*)alloc((size_t)2 * B_ * N3 * 4);       //  7.4 MB
  float*    h    = (float*)alloc((size_t)B_ * H_ * 4);
  half_t*   hh   = (half_t*)alloc(((size_t)B_ * KH + 64) * 2);   // +64 pad
  uint32_t* bar  = (uint32_t*)alloc(16384 * 4);                  // flags+rel

  gather_cast_x<<<(B_ * S_ * EP) / 256, 256, 0, stream>>>(tokens, emb, xb);
  convert_wi<<<(N3 * EP) / 256, 256, 0, stream>>>(Wir, Wii, Win, bir, bii, bin, Wi, bias);
  convert_wh<<<(N3 * KH) / 256, 256, 0, stream>>>(Whr, Whi, Whn, Wf);
  init_h<<<(B_ * H_) / 256, 256, 0, stream>>>(h, hh, bar);

  // Phase 1: gates_x = fp16( x @ W_i^T + b )   [6144 x 7200]
  gemm_x<<<dim3(48, 57), 256, 0, stream>>>(xb, Wi, gx, bias);

  // Phase 2: one persistent weight-stationary kernel runs all 48 steps
  gru_scan<<<NBLK, 256, 0, stream>>>(Wf, gx, Gp, h, hh, lengths, out, bar);
}